// Round 10
// baseline (576.511 us; speedup 1.0000x reference)
//
#include <hip/hip_runtime.h>
#include <hip/hip_bf16.h>
#include <cstdint>
#include <cstddef>

#define BB 4
#define TT 2048
#define DD 512
#define NEG_INF (-3.402823466e+38f)
#define POS_INF (3.402823466e+38f)

typedef __attribute__((ext_vector_type(8))) short bf16x8;
typedef __attribute__((ext_vector_type(8))) unsigned short ushort8;
typedef __attribute__((ext_vector_type(4))) float f32x4;

__device__ __forceinline__ float sigmoidf_(float x){ return 1.0f/(1.0f+expf(-x)); }

__device__ __forceinline__ unsigned short f2bf(float x){
  __hip_bfloat16 b = __float2bfloat16(x);
  return *reinterpret_cast<unsigned short*>(&b);
}

// monotonic float<->uint map (no NaNs in sim values)
__device__ __forceinline__ unsigned int fwd_map(float f){
  unsigned int b = __float_as_uint(f);
  return b ^ ((b & 0x80000000u) ? 0xFFFFFFFFu : 0x80000000u);
}
__device__ __forceinline__ float inv_map(unsigned int u){
  unsigned int b = (u & 0x80000000u) ? (u ^ 0x80000000u) : ~u;
  return __uint_as_float(b);
}

__device__ __forceinline__ unsigned long long shfl_xor64(unsigned long long x, int off){
  unsigned int hi = __shfl_xor((unsigned int)(x >> 32), off);
  unsigned int lo = __shfl_xor((unsigned int)x, off);
  return ((unsigned long long)hi << 32) | lo;
}

// ---------------- rnorm + bf16 hi/lo split of xn ----------------
__global__ __launch_bounds__(64) void k_normsplit(const float* __restrict__ h, float* __restrict__ rnorm,
                                                  unsigned short* __restrict__ Xh, unsigned short* __restrict__ Xl){
  int row = blockIdx.x;
  const float* hr = h + (size_t)row*DD;
  int lane = threadIdx.x;
  float4 v0 = *(const float4*)&hr[lane*4];
  float4 v1 = *(const float4*)&hr[lane*4 + 256];
  float ss = v0.x*v0.x+v0.y*v0.y+v0.z*v0.z+v0.w*v0.w
           + v1.x*v1.x+v1.y*v1.y+v1.z*v1.z+v1.w*v1.w;
  #pragma unroll
  for (int off=32; off; off>>=1) ss += __shfl_xor(ss, off);
  float rn = 1.0f / fmaxf(sqrtf(ss), 1e-12f);
  if (lane==0) rnorm[row] = rn;

  float xs[8] = {v0.x,v0.y,v0.z,v0.w,v1.x,v1.y,v1.z,v1.w};
  unsigned short hb[8], lb[8];
  #pragma unroll
  for (int q=0;q<8;q++){
    float xn = xs[q]*rn;
    unsigned short hh = f2bf(xn);
    __hip_bfloat16 bh = *reinterpret_cast<__hip_bfloat16*>(&hh);
    float rem = xn - __bfloat162float(bh);
    hb[q] = hh; lb[q] = f2bf(rem);
  }
  ushort4 h0 = {hb[0],hb[1],hb[2],hb[3]}, h1 = {hb[4],hb[5],hb[6],hb[7]};
  ushort4 l0 = {lb[0],lb[1],lb[2],lb[3]}, l1 = {lb[4],lb[5],lb[6],lb[7]};
  *(ushort4*)&Xh[(size_t)row*DD + lane*4]       = h0;
  *(ushort4*)&Xh[(size_t)row*DD + lane*4 + 256] = h1;
  *(ushort4*)&Xl[(size_t)row*DD + lane*4]       = l0;
  *(ushort4*)&Xl[(size_t)row*DD + lane*4 + 256] = l1;
}

// ---------------- sim via MFMA bf16 3-pass split, 128x128 tile ----------------
__global__ __launch_bounds__(256) void k_sim(const unsigned short* __restrict__ Xh,
                                             const unsigned short* __restrict__ Xl,
                                             float* __restrict__ sim, int b0){
  int p = blockIdx.x;
  int jt = (int)((sqrtf(8.0f*(float)p + 1.0f) - 1.0f)*0.5f);
  while ((jt+1)*(jt+2)/2 <= p) jt++;
  while (jt*(jt+1)/2 > p) jt--;
  int is = p - jt*(jt+1)/2;

  int bl = blockIdx.y;
  size_t xoff = (size_t)(b0 + bl)*TT*DD;
  const unsigned short* XhB = Xh + xoff;
  const unsigned short* XlB = Xl + xoff;
  float* simb = sim + (size_t)bl*TT*TT;
  int t0 = jt*128, s0 = is*128;

  __shared__ __align__(16) short As[128*32];
  __shared__ __align__(16) short Bs[128*32];

  int tid = threadIdx.x, wave = tid>>6, lane = tid&63;
  int wr = wave>>1, wc = wave&1;

  int srow = tid>>2;
  int sc8  = (tid&3)*8;

  f32x4 acc[4][4];
  #pragma unroll
  for (int m=0;m<4;m++)
    #pragma unroll
    for (int n=0;n<4;n++) acc[m][n] = (f32x4){0.f,0.f,0.f,0.f};

  ushort8 ra0, ra1, rb0, rb1;
  auto gload = [&](int s){
    int pass = s>>4; int kcol = (s&15)*32;
    const unsigned short* sA = (pass<2) ? XhB : XlB;
    const unsigned short* sB = (pass!=1) ? XhB : XlB;
    ra0 = *(const ushort8*)&sA[(size_t)(t0+srow)*DD + kcol + sc8];
    ra1 = *(const ushort8*)&sA[(size_t)(t0+srow+64)*DD + kcol + sc8];
    rb0 = *(const ushort8*)&sB[(size_t)(s0+srow)*DD + kcol + sc8];
    rb1 = *(const ushort8*)&sB[(size_t)(s0+srow+64)*DD + kcol + sc8];
  };

  gload(0);
  for (int s=0; s<48; ++s){
    __syncthreads();
    *(ushort8*)&As[srow*32 + sc8]      = ra0;
    *(ushort8*)&As[(srow+64)*32 + sc8] = ra1;
    *(ushort8*)&Bs[srow*32 + sc8]      = rb0;
    *(ushort8*)&Bs[(srow+64)*32 + sc8] = rb1;
    __syncthreads();
    if (s < 47) gload(s+1);

    int arow = wr*64 + (lane&15);
    int brow = wc*64 + (lane&15);
    int kb = (lane>>4)*8;
    bf16x8 af[4], bf[4];
    #pragma unroll
    for (int m=0;m<4;m++) af[m] = *(const bf16x8*)&As[(arow + m*16)*32 + kb];
    #pragma unroll
    for (int n=0;n<4;n++) bf[n] = *(const bf16x8*)&Bs[(brow + n*16)*32 + kb];
    #pragma unroll
    for (int m=0;m<4;m++)
      #pragma unroll
      for (int n=0;n<4;n++)
        acc[m][n] = __builtin_amdgcn_mfma_f32_16x16x32_bf16(af[m], bf[n], acc[m][n], 0, 0, 0);
  }

  #pragma unroll
  for (int m=0;m<4;m++){
    int t = t0 + wr*64 + m*16 + (lane>>4)*4;
    #pragma unroll
    for (int n=0;n<4;n++){
      int sc = s0 + wc*64 + n*16 + (lane&15);
      float* dst = simb + (size_t)t*TT + sc;
      #pragma unroll
      for (int j=0;j<4;j++) dst[(size_t)j*TT] = acc[m][n][j];
    }
  }
}

// ---------------- top-k: block-per-row cooperative fast path + verify; radix fallback ----------------
#define BMASK 0xFFFFFF00u
#define MKKEY(F,S) ((((unsigned long long)fwd_map(F)) << 32) | (unsigned int)(~(S)))
#define INS(KK) do{ unsigned long long a=(KK); \
  if (a > kv3){ \
    if (a > kv0){ unsigned long long tq=kv0; kv0=a; a=tq; } \
    if (a > kv1){ unsigned long long tq=kv1; kv1=a; a=tq; } \
    if (a > kv2){ unsigned long long tq=kv2; kv2=a; a=tq; } \
    kv3=a; } }while(0)

// 3-pass radix: exact 24-bit bucket of the k1-th largest key (key = fwd_map ^ flip); wave-level
__device__ __forceinline__ unsigned int radix24(const float* __restrict__ srow, int t, int k1,
                                                unsigned int flip, int* sh, int lane){
  #pragma unroll
  for (int i=0;i<4;i++) sh[lane + i*64] = 0;
  int t4 = t & ~3;
  for (int s4 = lane*4; s4 < t4; s4 += 256){
    float4 f = *(const float4*)&srow[s4];
    unsigned int u0=fwd_map(f.x)^flip, u1=fwd_map(f.y)^flip, u2=fwd_map(f.z)^flip, u3=fwd_map(f.w)^flip;
    atomicAdd(&sh[u0>>24],1); atomicAdd(&sh[u1>>24],1);
    atomicAdd(&sh[u2>>24],1); atomicAdd(&sh[u3>>24],1);
  }
  for (int s = t4 + lane; s < t; s += 64){
    unsigned int u = fwd_map(srow[s])^flip;
    atomicAdd(&sh[u>>24],1);
  }
  unsigned int pfx = 0u; int kp = k1;
  #pragma unroll
  for (int pass = 0; pass < 3; ++pass){
    int shift = 24 - 8*pass;
    int m4 = sh[4*lane] + sh[4*lane+1] + sh[4*lane+2] + sh[4*lane+3];
    int x = __shfl(m4, 63-lane);
    #pragma unroll
    for (int off = 1; off < 64; off <<= 1){
      int v = __shfl_up(x, off);
      if (lane >= off) x += v;
    }
    int T = __shfl(x, 63-lane);
    int G = T - m4;
    bool hit = (G < kp) && (kp <= T);
    unsigned int npfx = 0u; int nkp = 0;
    if (hit){
      int c = G; int D = 4*lane;
      #pragma unroll
      for (int i = 3; i >= 0; --i){
        int hc = sh[4*lane + i];
        if (kp <= c + hc){ D = 4*lane + i; break; }
        c += hc;
      }
      npfx = pfx | ((unsigned int)D << shift);
      nkp = kp - c;
    }
    unsigned long long hm = __ballot(hit);
    int src = __ffsll(hm) - 1;
    pfx = __shfl(npfx, src);
    kp  = __shfl(nkp, src);
    if (pass == 2) break;

    int nshift = shift - 8;
    unsigned int keep = 0xFFFFFFFFu << shift;
    #pragma unroll
    for (int i=0;i<4;i++) sh[lane + i*64] = 0;
    for (int s4 = lane*4; s4 < t4; s4 += 256){
      float4 f = *(const float4*)&srow[s4];
      unsigned int u0=fwd_map(f.x)^flip, u1=fwd_map(f.y)^flip, u2=fwd_map(f.z)^flip, u3=fwd_map(f.w)^flip;
      if (((u0 ^ pfx) & keep) == 0) atomicAdd(&sh[(u0>>nshift)&255],1);
      if (((u1 ^ pfx) & keep) == 0) atomicAdd(&sh[(u1>>nshift)&255],1);
      if (((u2 ^ pfx) & keep) == 0) atomicAdd(&sh[(u2>>nshift)&255],1);
      if (((u3 ^ pfx) & keep) == 0) atomicAdd(&sh[(u3>>nshift)&255],1);
    }
    for (int s = t4 + lane; s < t; s += 64){
      unsigned int u = fwd_map(srow[s])^flip;
      if (((u ^ pfx) & keep) == 0) atomicAdd(&sh[(u>>nshift)&255],1);
    }
  }
  return pfx;   // low 8 bits zero
}

template<int ESIM, int ECON>
__global__ __launch_bounds__(256) void k_topk(const float* __restrict__ sim, int b0,
                                              const float* __restrict__ h, const float* __restrict__ rnorm,
                                              int* __restrict__ topidx, int* __restrict__ botidx,
                                              int* __restrict__ bcnt){
  constexpr int K1  = ESIM + 8;
  constexpr int K1B = ESIM + ECON + 8;       // <= 32
  constexpr int CANDCAP = 40;
  constexpr int EQCAP = 44;
  constexpr int NP = ESIM + 1;
  constexpr float TAU = 5e-5f;

  __shared__ unsigned long long s_keys[4*NP];
  __shared__ unsigned long long s_keyLast;
  __shared__ int s_cntTot;
  __shared__ int s_hist[256];
  __shared__ int s_cand[CANDCAP];
  __shared__ int s_eq[EQCAP];
  __shared__ int s_sel[ESIM];
  __shared__ int s_bot[16];
  __shared__ int s_cnt[2];

  int tid = threadIdx.x, lane = tid & 63, wid = tid >> 6;
  int lrow = blockIdx.x;
  int bl = lrow >> 11, t = lrow & (TT-1);
  int gb = b0 + bl;
  int grow = (gb << 11) | t;

  if (t <= ESIM){                       // uniform per block: safe early exit
    if (tid < t) topidx[(size_t)grow*16 + tid] = tid;
    if (tid == 0) bcnt[grow] = 0;
    return;
  }
  const float* srow = sim + (size_t)lrow*TT;
  const float* hb  = h + (size_t)gb*TT*DD;
  const float* rnb = rnorm + (size_t)gb*TT;
  int t4 = t & ~3;

  if (tid == 0) s_cntTot = 0;

  // ---- select scan: block-strided per-lane top-4 (64-bit keys) ----
  unsigned long long kv0=0, kv1=0, kv2=0, kv3=0;
  for (int s4 = tid*4; s4 < t4; s4 += 1024){
    float4 f = *(const float4*)&srow[s4];
    INS(MKKEY(f.x,s4)); INS(MKKEY(f.y,s4+1)); INS(MKKEY(f.z,s4+2)); INS(MKKEY(f.w,s4+3));
  }
  for (int s = t4 + tid; s < t; s += 256) INS(MKKEY(srow[s],s));

  // ---- per-wave pop NP keys into LDS ----
  #pragma unroll
  for (int k = 0; k < NP; ++k){
    unsigned long long bk = kv0;
    #pragma unroll
    for (int off=32; off; off>>=1){
      unsigned long long ok = shfl_xor64(bk, off);
      if (ok > bk) bk = ok;
    }
    if (kv0 == bk){ kv0=kv1; kv1=kv2; kv2=kv3; kv3=0ull; }
    if (lane == 0) s_keys[wid*NP + k] = bk;
  }
  __syncthreads();

  // ---- wave 0 merges 4*NP keys -> global top-NP ----
  int myidx = 0x7fffffff;
  float vA = 0.f, vB = 0.f;
  if (wid == 0){
    constexpr int NL = 4*NP;
    unsigned long long m0 = (lane < NL) ? s_keys[lane] : 0ull;
    unsigned long long m1 = (lane + 64 < NL) ? s_keys[lane + 64] : 0ull;
    if (m1 > m0){ unsigned long long tq=m0; m0=m1; m1=tq; }
    unsigned long long keyLast = 0ull;
    #pragma unroll
    for (int k = 0; k < NP; ++k){
      unsigned long long bk = m0;
      #pragma unroll
      for (int off=32; off; off>>=1){
        unsigned long long ok = shfl_xor64(bk, off);
        if (ok > bk) bk = ok;
      }
      if (m0 == bk){ m0 = m1; m1 = 0ull; }
      if (lane == k) myidx = (int)(~(unsigned int)bk);
      if (k == ESIM-1) vA = inv_map((unsigned int)(bk >> 32));
      if (k == ESIM){ vB = inv_map((unsigned int)(bk >> 32)); keyLast = bk; }
    }
    if (lane == 0) s_keyLast = keyLast;
  }
  __syncthreads();

  // ---- cooperative exact count of keys > keyLast ----
  {
    unsigned long long kL = s_keyLast;
    int cnt = 0;
    for (int s4 = tid*4; s4 < t4; s4 += 1024){
      float4 f = *(const float4*)&srow[s4];
      cnt += (MKKEY(f.x,s4)   > kL);
      cnt += (MKKEY(f.y,s4+1) > kL);
      cnt += (MKKEY(f.z,s4+2) > kL);
      cnt += (MKKEY(f.w,s4+3) > kL);
    }
    for (int s = t4 + tid; s < t; s += 256) cnt += (MKKEY(srow[s],s) > kL);
    #pragma unroll
    for (int off=32; off; off>>=1) cnt += __shfl_xor(cnt, off);
    if (lane == 0) atomicAdd(&s_cntTot, cnt);
  }
  __syncthreads();

  if (wid != 0) return;                 // wave 0 finishes the row (no barriers below)

  int* sh    = s_hist;
  int* scand = s_cand;
  int* seq   = s_eq;
  int* ssel  = s_sel;
  int* sbot  = s_bot;

  bool fb = (s_cntTot != ESIM) || (vA - vB < TAU);
  if (!fb){
    if (lane < ESIM){
      ssel[lane] = myidx;
      topidx[(size_t)grow*16 + lane] = myidx;
    }
  } else {
    // ========== FALLBACK: radix24 + collect + extract + gap/rescore (wave 0) ==========
    int k1 = min(t, K1);
    unsigned int thr = radix24(srow, t, k1, 0u, sh, lane);

    if (lane == 0){ s_cnt[0] = 0; s_cnt[1] = 0; }
    for (int s4 = lane*4; s4 < t4; s4 += 256){
      float4 f = *(const float4*)&srow[s4];
      unsigned int uu[4] = {fwd_map(f.x), fwd_map(f.y), fwd_map(f.z), fwd_map(f.w)};
      #pragma unroll
      for (int q=0;q<4;q++){
        unsigned int b24 = uu[q] & BMASK;
        if (b24 > thr){ int p = atomicAdd(&s_cnt[0],1); if (p < CANDCAP) scand[p] = s4+q; }
        else if (b24 == thr){ int p = atomicAdd(&s_cnt[1],1); if (p < EQCAP) seq[p] = s4+q; }
      }
    }
    for (int s = t4 + lane; s < t; s += 64){
      unsigned int b24 = fwd_map(srow[s]) & BMASK;
      if (b24 > thr){ int p = atomicAdd(&s_cnt[0],1); if (p < CANDCAP) scand[p] = s; }
      else if (b24 == thr){ int p = atomicAdd(&s_cnt[1],1); if (p < EQCAP) seq[p] = s; }
    }
    int c_gt = min(s_cnt[0], CANDCAP);
    int c_eq = min(s_cnt[1], EQCAP);
    int ncand = min(c_gt + c_eq, 64);

    unsigned int myu = 0u; int myi = 0x7fffffff;
    if (lane < ncand){
      myi = (lane < c_gt) ? scand[lane] : seq[lane - c_gt];
      myu = fwd_map(srow[myi]);
    }

    float fvA = 0.f, fvB = 0.f;
    {
      unsigned int cu = myu; int ci = myi;
      #pragma unroll
      for (int k = 0; k <= ESIM; ++k){
        unsigned int bu = cu; int bi = ci;
        #pragma unroll
        for (int off=32; off; off>>=1){
          unsigned int ou = __shfl_xor(bu, off); int oi = __shfl_xor(bi, off);
          if (ou > bu || (ou == bu && oi < bi)){ bu = ou; bi = oi; }
        }
        if (k < ESIM && lane == 0) ssel[k] = bi;
        if (k == ESIM-1) fvA = inv_map(bu);
        if (k == ESIM)   fvB = inv_map(bu);
        if (ci == bi){ cu = 0u; ci = 0x7fffffff; }
      }
    }

    bool resc = (fvA - fvB < TAU);
    if (resc){
      const float* hq = hb + (size_t)t*DD;
      float rt = rnb[t];
      float4 q0 = *(const float4*)&hq[lane*4];
      float4 q1 = *(const float4*)&hq[lane*4 + 256];
      float ev = NEG_INF;
      for (int j = 0; j < ncand; ++j){
        int idx = (j < c_gt) ? scand[j] : seq[j - c_gt];
        const float* hc = hb + (size_t)idx*DD;
        float4 c0 = *(const float4*)&hc[lane*4];
        float4 c1 = *(const float4*)&hc[lane*4 + 256];
        float pp = q0.x*c0.x+q0.y*c0.y+q0.z*c0.z+q0.w*c0.w
                 + q1.x*c1.x+q1.y*c1.y+q1.z*c1.z+q1.w*c1.w;
        #pragma unroll
        for (int off=32; off; off>>=1) pp += __shfl_xor(pp, off);
        float ex = pp * rt * rnb[idx];
        if (lane == j) ev = ex;
      }
      float rv = (lane < ncand) ? ev : NEG_INF;
      int   ri = myi;
      #pragma unroll
      for (int k = 0; k < ESIM; ++k){
        float bv = rv; int bi = ri;
        #pragma unroll
        for (int off=32; off; off>>=1){
          float ov = __shfl_xor(bv, off); int oi = __shfl_xor(bi, off);
          if (ov > bv || (ov == bv && oi < bi)){ bv = ov; bi = oi; }
        }
        if (lane == 0) ssel[k] = bi;
        if (ri == bi) rv = NEG_INF;
      }
    }
    if (lane < ESIM) topidx[(size_t)grow*16 + lane] = ssel[lane];
  }

  // ---------- BOTTOM path (rows with t > TT-ECON only, <=7 per batch) ----------
  int need = ECON - (TT - t);
  int cnt2 = 0;
  if (need > 0){
    constexpr unsigned int FLIP = 0xFFFFFFFFu;
    int k1b = min(t, K1B);
    unsigned int thrb = radix24(srow, t, k1b, FLIP, sh, lane);

    if (lane == 0){ s_cnt[0] = 0; s_cnt[1] = 0; }
    for (int s4 = lane*4; s4 < t4; s4 += 256){
      float4 f = *(const float4*)&srow[s4];
      unsigned int uu[4] = {fwd_map(f.x)^FLIP, fwd_map(f.y)^FLIP, fwd_map(f.z)^FLIP, fwd_map(f.w)^FLIP};
      #pragma unroll
      for (int q=0;q<4;q++){
        unsigned int b24 = uu[q] & BMASK;
        if (b24 > thrb){ int p = atomicAdd(&s_cnt[0],1); if (p < CANDCAP) scand[p] = s4+q; }
        else if (b24 == thrb){ int p = atomicAdd(&s_cnt[1],1); if (p < EQCAP) seq[p] = s4+q; }
      }
    }
    for (int s = t4 + lane; s < t; s += 64){
      unsigned int u = fwd_map(srow[s])^FLIP;
      unsigned int b24 = u & BMASK;
      if (b24 > thrb){ int p = atomicAdd(&s_cnt[0],1); if (p < CANDCAP) scand[p] = s; }
      else if (b24 == thrb){ int p = atomicAdd(&s_cnt[1],1); if (p < EQCAP) seq[p] = s; }
    }
    int bc_gt = min(s_cnt[0], CANDCAP);
    int bc_eq = min(s_cnt[1], EQCAP);
    int ncb = min(bc_gt + bc_eq, 64);

    unsigned int mu = 0u; int mi = 0x7fffffff;
    if (lane < ncb){
      mi = (lane < bc_gt) ? scand[lane] : seq[lane - bc_gt];
      mu = fwd_map(srow[mi]) ^ FLIP;
    }
    float wA = 0.f, wB = 0.f;
    unsigned int cu = mu; int ci = mi;
    #pragma unroll
    for (int k = 0; k < K1B; ++k){
      if (k < ncb && cnt2 < need + 8){
        unsigned int bu = cu; int bi = ci;
        #pragma unroll
        for (int off=32; off; off>>=1){
          unsigned int ou = __shfl_xor(bu, off); int oi = __shfl_xor(bi, off);
          if (ou > bu || (ou == bu && oi < bi)){ bu = ou; bi = oi; }
        }
        if (ci == bi){ cu = 0u; ci = 0x7fffffff; }
        bool mem = false;
        #pragma unroll
        for (int j=0;j<ESIM;j++) if (ssel[j] == bi) mem = true;
        if (!mem){
          if (lane == 0) sbot[cnt2] = bi;
          float val = inv_map(bu ^ FLIP);
          if (cnt2 == need-1) wA = val;
          if (cnt2 == need)   wB = val;
          cnt2++;
        }
      }
    }
    int npick = min(need, cnt2);
    bool rb = (cnt2 > need) && (wB - wA < TAU);
    if (!rb){
      if (lane < npick) botidx[(size_t)grow*8 + lane] = sbot[lane];
    } else {
      const float* hq = hb + (size_t)t*DD;
      float rt = rnb[t];
      float4 q0 = *(const float4*)&hq[lane*4];
      float4 q1 = *(const float4*)&hq[lane*4 + 256];
      float ev = POS_INF; int ei = 0x7fffffff;
      for (int j = 0; j < cnt2; ++j){
        int idx = sbot[j];
        const float* hc = hb + (size_t)idx*DD;
        float4 c0 = *(const float4*)&hc[lane*4];
        float4 c1 = *(const float4*)&hc[lane*4 + 256];
        float pp = q0.x*c0.x+q0.y*c0.y+q0.z*c0.z+q0.w*c0.w
                 + q1.x*c1.x+q1.y*c1.y+q1.z*c1.z+q1.w*c1.w;
        #pragma unroll
        for (int off=32; off; off>>=1) pp += __shfl_xor(pp, off);
        float ex = pp * rt * rnb[idx];
        if (lane == j){ ev = ex; ei = idx; }
      }
      #pragma unroll
      for (int k = 0; k < ECON; ++k){
        if (k < npick){
          float bv = ev; int bi = ei;
          #pragma unroll
          for (int off=32; off; off>>=1){
            float ov = __shfl_xor(bv, off); int oi = __shfl_xor(bi, off);
            if (ov < bv || (ov == bv && oi < bi)){ bv = ov; bi = oi; }
          }
          if (lane == 0) botidx[(size_t)grow*8 + k] = bi;
          if (ei == bi) ev = POS_INF;
        }
      }
    }
    cnt2 = npick;
  }
  if (lane == 0) bcnt[grow] = cnt2;
}

// ---------------- aggregate + blend + gelu + momentum ----------------
__global__ __launch_bounds__(256) void k_agg(const float* __restrict__ hsrc, float* __restrict__ hdst,
                                             const int* __restrict__ topidx, const int* __restrict__ botidx,
                                             const int* __restrict__ bcnt,
                                             const float* __restrict__ gain, const float* __restrict__ bias,
                                             const float* __restrict__ log_mix, const float* __restrict__ log_alpha,
                                             const float* __restrict__ log_momentum, int r, int eff_sim){
  int row = blockIdx.x;
  int b = row >> 11; int t = row & (TT-1);
  int n_sim = min(eff_sim, t);
  int n_con = bcnt[row];
  float mix      = sigmoidf_(log_mix[r]);
  float alpha    = sigmoidf_(log_alpha[r]);
  float momentum = sigmoidf_(log_momentum[0]);
  const float* hb = hsrc + (size_t)b*TT*DD;

  __shared__ int sidx[16];
  __shared__ int scidx[8];
  if (threadIdx.x < 16) sidx[threadIdx.x]  = (threadIdx.x < n_sim) ? topidx[(size_t)row*16 + threadIdx.x] : 0;
  if (threadIdx.x < 8)  scidx[threadIdx.x] = (threadIdx.x < n_con) ? botidx[(size_t)row*8  + threadIdx.x] : 0;
  __syncthreads();

  #pragma unroll
  for (int e = threadIdx.x; e < DD; e += 256){
    float sp = 0.f;
    for (int j=0;j<n_sim;j++) sp += hb[(size_t)sidx[j]*DD + e];
    float sn = 0.f;
    for (int j=0;j<n_con;j++) sn += hb[(size_t)scidx[j]*DD + e];
    float mp = sp / (float)max(n_sim, 1);
    float mn = sn / (float)max(n_con, 1);
    float ctx = alpha*mp + (1.f-alpha)*mn;
    float hv = hsrc[(size_t)row*DD + e];
    float blended = mix*hv + (1.f-mix)*ctx;
    float u = blended*gain[e] + bias[e];
    float g = 0.5f*u*(1.0f + erff(u*0.7071067811865475f));
    hdst[(size_t)row*DD + e] = momentum*hv + (1.f-momentum)*g;
  }
}

// ---------------- out = (h - x) * scale ----------------
__global__ __launch_bounds__(256) void k_final(const float* __restrict__ hfin, const float* __restrict__ x,
                                               const float* __restrict__ log_scale, float* __restrict__ out, int n){
  float scale = log1pf(expf(log_scale[0])) + 0.01f;
  int i = blockIdx.x*256 + threadIdx.x;
  if (i < n) out[i] = (hfin[i] - x[i]) * scale;
}

extern "C" void kernel_launch(void* const* d_in, const int* in_sizes, int n_in,
                              void* d_out, int out_size, void* d_ws, size_t ws_size,
                              hipStream_t stream) {
  const float* x         = (const float*)d_in[0];
  const float* gain      = (const float*)d_in[1];
  const float* bias      = (const float*)d_in[2];
  const float* log_mix   = (const float*)d_in[3];
  const float* log_alpha = (const float*)d_in[4];
  const float* log_mom   = (const float*)d_in[5];
  const float* log_scale = (const float*)d_in[6];

  float* hA = (float*)d_out;
  char* ws = (char*)d_ws;
  size_t off = 0;
  auto alloc = [&](size_t bytes){ void* p = ws + off; off += (bytes + 255) & ~(size_t)255; return p; };

  float*          hB     = (float*)alloc((size_t)BB*TT*DD*4);
  float*          rnorm  = (float*)alloc((size_t)BB*TT*4);
  int*            topidx = (int*)  alloc((size_t)BB*TT*16*4);
  int*            botidx = (int*)  alloc((size_t)BB*TT*8*4);
  int*            bcnt   = (int*)  alloc((size_t)BB*TT*4);
  unsigned short* Xh     = (unsigned short*)alloc((size_t)BB*TT*DD*2);
  unsigned short* Xl     = (unsigned short*)alloc((size_t)BB*TT*DD*2);

  size_t rem = (ws_size > off) ? (ws_size - off) : 0;
  int cb = (int)(rem / ((size_t)TT*TT*4));
  if (cb < 1) cb = 1;
  if (cb > BB) cb = BB;
  float* sim = (float*)alloc((size_t)cb*TT*TT*4);

  const float* hsrc = x;
  float* hdst = hB;
  const int ks[3] = {4, 8, 16};

  for (int r = 0; r < 3; ++r){
    k_normsplit<<<BB*TT, 64, 0, stream>>>(hsrc, rnorm, Xh, Xl);
    for (int b0 = 0; b0 < BB; b0 += cb){
      int nb = (BB - b0 < cb) ? (BB - b0) : cb;
      dim3 g(136, nb);
      k_sim<<<g, 256, 0, stream>>>(Xh, Xl, sim, b0);
      if (r == 0)      k_topk<4,2><<<nb*TT, 256, 0, stream>>>(sim, b0, hsrc, rnorm, topidx, botidx, bcnt);
      else if (r == 1) k_topk<8,4><<<nb*TT, 256, 0, stream>>>(sim, b0, hsrc, rnorm, topidx, botidx, bcnt);
      else             k_topk<16,8><<<nb*TT, 256, 0, stream>>>(sim, b0, hsrc, rnorm, topidx, botidx, bcnt);
    }
    k_agg<<<BB*TT, 256, 0, stream>>>(hsrc, hdst, topidx, botidx, bcnt,
                                     gain + (size_t)r*DD, bias + (size_t)r*DD,
                                     log_mix, log_alpha, log_mom, r, ks[r]);
    if (r == 0){ hsrc = hB; hdst = hA; }
    else if (r == 1){ hsrc = hA; hdst = hB; }
  }
  k_final<<<(BB*TT*DD)/256, 256, 0, stream>>>(hB, x, log_scale, (float*)d_out, BB*TT*DD);
}

// Round 11
// 462.387 us; speedup vs baseline: 1.2468x; 1.2468x over previous
//
#include <hip/hip_runtime.h>
#include <hip/hip_bf16.h>
#include <cstdint>
#include <cstddef>

#define BB 4
#define TT 2048
#define DD 512
#define NEG_INF (-3.402823466e+38f)
#define POS_INF (3.402823466e+38f)

typedef __attribute__((ext_vector_type(8))) short bf16x8;
typedef __attribute__((ext_vector_type(8))) unsigned short ushort8;
typedef __attribute__((ext_vector_type(4))) float f32x4;

__device__ __forceinline__ float sigmoidf_(float x){ return 1.0f/(1.0f+expf(-x)); }

__device__ __forceinline__ unsigned short f2bf(float x){
  __hip_bfloat16 b = __float2bfloat16(x);
  return *reinterpret_cast<unsigned short*>(&b);
}

// monotonic float<->uint map (no NaNs in sim values)
__device__ __forceinline__ unsigned int fwd_map(float f){
  unsigned int b = __float_as_uint(f);
  return b ^ ((b & 0x80000000u) ? 0xFFFFFFFFu : 0x80000000u);
}
__device__ __forceinline__ float inv_map(unsigned int u){
  unsigned int b = (u & 0x80000000u) ? (u ^ 0x80000000u) : ~u;
  return __uint_as_float(b);
}

__device__ __forceinline__ unsigned long long shfl_xor64(unsigned long long x, int off){
  unsigned int hi = __shfl_xor((unsigned int)(x >> 32), off);
  unsigned int lo = __shfl_xor((unsigned int)x, off);
  return ((unsigned long long)hi << 32) | lo;
}

// ---------------- rnorm + bf16 hi/lo split of xn ----------------
__global__ __launch_bounds__(64) void k_normsplit(const float* __restrict__ h, float* __restrict__ rnorm,
                                                  unsigned short* __restrict__ Xh, unsigned short* __restrict__ Xl){
  int row = blockIdx.x;
  const float* hr = h + (size_t)row*DD;
  int lane = threadIdx.x;
  float4 v0 = *(const float4*)&hr[lane*4];
  float4 v1 = *(const float4*)&hr[lane*4 + 256];
  float ss = v0.x*v0.x+v0.y*v0.y+v0.z*v0.z+v0.w*v0.w
           + v1.x*v1.x+v1.y*v1.y+v1.z*v1.z+v1.w*v1.w;
  #pragma unroll
  for (int off=32; off; off>>=1) ss += __shfl_xor(ss, off);
  float rn = 1.0f / fmaxf(sqrtf(ss), 1e-12f);
  if (lane==0) rnorm[row] = rn;

  float xs[8] = {v0.x,v0.y,v0.z,v0.w,v1.x,v1.y,v1.z,v1.w};
  unsigned short hb[8], lb[8];
  #pragma unroll
  for (int q=0;q<8;q++){
    float xn = xs[q]*rn;
    unsigned short hh = f2bf(xn);
    __hip_bfloat16 bh = *reinterpret_cast<__hip_bfloat16*>(&hh);
    float rem = xn - __bfloat162float(bh);
    hb[q] = hh; lb[q] = f2bf(rem);
  }
  ushort4 h0 = {hb[0],hb[1],hb[2],hb[3]}, h1 = {hb[4],hb[5],hb[6],hb[7]};
  ushort4 l0 = {lb[0],lb[1],lb[2],lb[3]}, l1 = {lb[4],lb[5],lb[6],lb[7]};
  *(ushort4*)&Xh[(size_t)row*DD + lane*4]       = h0;
  *(ushort4*)&Xh[(size_t)row*DD + lane*4 + 256] = h1;
  *(ushort4*)&Xl[(size_t)row*DD + lane*4]       = l0;
  *(ushort4*)&Xl[(size_t)row*DD + lane*4 + 256] = l1;
}

// ---------------- sim via MFMA bf16 3-pass split, 128x128 tile ----------------
__global__ __launch_bounds__(256) void k_sim(const unsigned short* __restrict__ Xh,
                                             const unsigned short* __restrict__ Xl,
                                             float* __restrict__ sim, int b0){
  int p = blockIdx.x;
  int jt = (int)((sqrtf(8.0f*(float)p + 1.0f) - 1.0f)*0.5f);
  while ((jt+1)*(jt+2)/2 <= p) jt++;
  while (jt*(jt+1)/2 > p) jt--;
  int is = p - jt*(jt+1)/2;

  int bl = blockIdx.y;
  size_t xoff = (size_t)(b0 + bl)*TT*DD;
  const unsigned short* XhB = Xh + xoff;
  const unsigned short* XlB = Xl + xoff;
  float* simb = sim + (size_t)bl*TT*TT;
  int t0 = jt*128, s0 = is*128;

  __shared__ __align__(16) short As[128*32];
  __shared__ __align__(16) short Bs[128*32];

  int tid = threadIdx.x, wave = tid>>6, lane = tid&63;
  int wr = wave>>1, wc = wave&1;

  int srow = tid>>2;
  int sc8  = (tid&3)*8;

  f32x4 acc[4][4];
  #pragma unroll
  for (int m=0;m<4;m++)
    #pragma unroll
    for (int n=0;n<4;n++) acc[m][n] = (f32x4){0.f,0.f,0.f,0.f};

  ushort8 ra0, ra1, rb0, rb1;
  auto gload = [&](int s){
    int pass = s>>4; int kcol = (s&15)*32;
    const unsigned short* sA = (pass<2) ? XhB : XlB;
    const unsigned short* sB = (pass!=1) ? XhB : XlB;
    ra0 = *(const ushort8*)&sA[(size_t)(t0+srow)*DD + kcol + sc8];
    ra1 = *(const ushort8*)&sA[(size_t)(t0+srow+64)*DD + kcol + sc8];
    rb0 = *(const ushort8*)&sB[(size_t)(s0+srow)*DD + kcol + sc8];
    rb1 = *(const ushort8*)&sB[(size_t)(s0+srow+64)*DD + kcol + sc8];
  };

  gload(0);
  for (int s=0; s<48; ++s){
    __syncthreads();
    *(ushort8*)&As[srow*32 + sc8]      = ra0;
    *(ushort8*)&As[(srow+64)*32 + sc8] = ra1;
    *(ushort8*)&Bs[srow*32 + sc8]      = rb0;
    *(ushort8*)&Bs[(srow+64)*32 + sc8] = rb1;
    __syncthreads();
    if (s < 47) gload(s+1);

    int arow = wr*64 + (lane&15);
    int brow = wc*64 + (lane&15);
    int kb = (lane>>4)*8;
    bf16x8 af[4], bf[4];
    #pragma unroll
    for (int m=0;m<4;m++) af[m] = *(const bf16x8*)&As[(arow + m*16)*32 + kb];
    #pragma unroll
    for (int n=0;n<4;n++) bf[n] = *(const bf16x8*)&Bs[(brow + n*16)*32 + kb];
    #pragma unroll
    for (int m=0;m<4;m++)
      #pragma unroll
      for (int n=0;n<4;n++)
        acc[m][n] = __builtin_amdgcn_mfma_f32_16x16x32_bf16(af[m], bf[n], acc[m][n], 0, 0, 0);
  }

  #pragma unroll
  for (int m=0;m<4;m++){
    int t = t0 + wr*64 + m*16 + (lane>>4)*4;
    #pragma unroll
    for (int n=0;n<4;n++){
      int sc = s0 + wc*64 + n*16 + (lane&15);
      float* dst = simb + (size_t)t*TT + sc;
      #pragma unroll
      for (int j=0;j<4;j++) dst[(size_t)j*TT] = acc[m][n][j];
    }
  }
}

// ---------------- top-k: wave-per-row, single-sweep top-4 + certificate; radix fallback ----------------
#define BMASK 0xFFFFFF00u
#define MKKEY(F,S) ((((unsigned long long)fwd_map(F)) << 32) | (unsigned int)(~(S)))
#define INS(KK) do{ unsigned long long a=(KK); \
  if (a > kv3){ \
    if (a > kv0){ unsigned long long tq=kv0; kv0=a; a=tq; } \
    if (a > kv1){ unsigned long long tq=kv1; kv1=a; a=tq; } \
    if (a > kv2){ unsigned long long tq=kv2; kv2=a; a=tq; } \
    kv3=a; } }while(0)

// 3-pass radix: exact 24-bit bucket of the k1-th largest key (key = fwd_map ^ flip); wave-level
__device__ __forceinline__ unsigned int radix24(const float* __restrict__ srow, int t, int k1,
                                                unsigned int flip, int* sh, int lane){
  #pragma unroll
  for (int i=0;i<4;i++) sh[lane + i*64] = 0;
  int t4 = t & ~3;
  for (int s4 = lane*4; s4 < t4; s4 += 256){
    float4 f = *(const float4*)&srow[s4];
    unsigned int u0=fwd_map(f.x)^flip, u1=fwd_map(f.y)^flip, u2=fwd_map(f.z)^flip, u3=fwd_map(f.w)^flip;
    atomicAdd(&sh[u0>>24],1); atomicAdd(&sh[u1>>24],1);
    atomicAdd(&sh[u2>>24],1); atomicAdd(&sh[u3>>24],1);
  }
  for (int s = t4 + lane; s < t; s += 64){
    unsigned int u = fwd_map(srow[s])^flip;
    atomicAdd(&sh[u>>24],1);
  }
  unsigned int pfx = 0u; int kp = k1;
  #pragma unroll
  for (int pass = 0; pass < 3; ++pass){
    int shift = 24 - 8*pass;
    int m4 = sh[4*lane] + sh[4*lane+1] + sh[4*lane+2] + sh[4*lane+3];
    int x = __shfl(m4, 63-lane);
    #pragma unroll
    for (int off = 1; off < 64; off <<= 1){
      int v = __shfl_up(x, off);
      if (lane >= off) x += v;
    }
    int T = __shfl(x, 63-lane);
    int G = T - m4;
    bool hit = (G < kp) && (kp <= T);
    unsigned int npfx = 0u; int nkp = 0;
    if (hit){
      int c = G; int D = 4*lane;
      #pragma unroll
      for (int i = 3; i >= 0; --i){
        int hc = sh[4*lane + i];
        if (kp <= c + hc){ D = 4*lane + i; break; }
        c += hc;
      }
      npfx = pfx | ((unsigned int)D << shift);
      nkp = kp - c;
    }
    unsigned long long hm = __ballot(hit);
    int src = __ffsll(hm) - 1;
    pfx = __shfl(npfx, src);
    kp  = __shfl(nkp, src);
    if (pass == 2) break;

    int nshift = shift - 8;
    unsigned int keep = 0xFFFFFFFFu << shift;
    #pragma unroll
    for (int i=0;i<4;i++) sh[lane + i*64] = 0;
    for (int s4 = lane*4; s4 < t4; s4 += 256){
      float4 f = *(const float4*)&srow[s4];
      unsigned int u0=fwd_map(f.x)^flip, u1=fwd_map(f.y)^flip, u2=fwd_map(f.z)^flip, u3=fwd_map(f.w)^flip;
      if (((u0 ^ pfx) & keep) == 0) atomicAdd(&sh[(u0>>nshift)&255],1);
      if (((u1 ^ pfx) & keep) == 0) atomicAdd(&sh[(u1>>nshift)&255],1);
      if (((u2 ^ pfx) & keep) == 0) atomicAdd(&sh[(u2>>nshift)&255],1);
      if (((u3 ^ pfx) & keep) == 0) atomicAdd(&sh[(u3>>nshift)&255],1);
    }
    for (int s = t4 + lane; s < t; s += 64){
      unsigned int u = fwd_map(srow[s])^flip;
      if (((u ^ pfx) & keep) == 0) atomicAdd(&sh[(u>>nshift)&255],1);
    }
  }
  return pfx;   // low 8 bits zero
}

template<int ESIM, int ECON>
__global__ __launch_bounds__(256) void k_topk(const float* __restrict__ sim, int b0,
                                              const float* __restrict__ h, const float* __restrict__ rnorm,
                                              int* __restrict__ topidx, int* __restrict__ botidx,
                                              int* __restrict__ bcnt){
  constexpr int K1  = ESIM + 8;
  constexpr int K1B = ESIM + ECON + 8;       // <= 32
  constexpr int CANDCAP = 40;
  constexpr int EQCAP = 44;
  constexpr float TAU = 5e-5f;
  __shared__ int s_hist[4][256];
  __shared__ int s_cand[4][CANDCAP];
  __shared__ int s_eq[4][EQCAP];
  __shared__ int s_sel[4][ESIM];
  __shared__ int s_bot[4][16];
  __shared__ int s_cnt[4][2];

  int tid = threadIdx.x, lane = tid & 63, wid = tid >> 6;
  int lrow = blockIdx.x*4 + wid;
  int bl = lrow >> 11, t = lrow & (TT-1);
  int gb = b0 + bl;
  int grow = (gb << 11) | t;

  if (t <= ESIM){
    if (lane < t) topidx[(size_t)grow*16 + lane] = lane;
    if (lane == 0) bcnt[grow] = 0;
    return;
  }
  const float* srow = sim + (size_t)lrow*TT;
  const float* hb  = h + (size_t)gb*TT*DD;
  const float* rnb = rnorm + (size_t)gb*TT;

  int* sh    = s_hist[wid];
  int* scand = s_cand[wid];
  int* seq   = s_eq[wid];
  int* ssel  = s_sel[wid];
  int* sbot  = s_bot[wid];
  int t4 = t & ~3;

  // ========== FAST TOP PATH: single sweep, per-lane top-4, 4x-unrolled loads ==========
  unsigned long long kv0=0, kv1=0, kv2=0, kv3=0;
  {
    int s4 = lane*4;
    for (; s4 + 772 <= t4; s4 += 1024){
      float4 f0 = *(const float4*)&srow[s4];
      float4 f1 = *(const float4*)&srow[s4+256];
      float4 f2 = *(const float4*)&srow[s4+512];
      float4 f3 = *(const float4*)&srow[s4+768];
      INS(MKKEY(f0.x,s4));     INS(MKKEY(f0.y,s4+1));   INS(MKKEY(f0.z,s4+2));   INS(MKKEY(f0.w,s4+3));
      INS(MKKEY(f1.x,s4+256)); INS(MKKEY(f1.y,s4+257)); INS(MKKEY(f1.z,s4+258)); INS(MKKEY(f1.w,s4+259));
      INS(MKKEY(f2.x,s4+512)); INS(MKKEY(f2.y,s4+513)); INS(MKKEY(f2.z,s4+514)); INS(MKKEY(f2.w,s4+515));
      INS(MKKEY(f3.x,s4+768)); INS(MKKEY(f3.y,s4+769)); INS(MKKEY(f3.z,s4+770)); INS(MKKEY(f3.w,s4+771));
    }
    for (; s4 < t4; s4 += 256){
      float4 f = *(const float4*)&srow[s4];
      INS(MKKEY(f.x,s4)); INS(MKKEY(f.y,s4+1)); INS(MKKEY(f.z,s4+2)); INS(MKKEY(f.w,s4+3));
    }
    for (int s = t4 + lane; s < t; s += 64) INS(MKKEY(srow[s],s));
  }

  // certificate: kv3 bounds (strictly above) every key this lane ever discarded
  unsigned long long cert = kv3;
  #pragma unroll
  for (int off=32; off; off>>=1){
    unsigned long long oc = shfl_xor64(cert, off);
    if (oc > cert) cert = oc;
  }

  int myidx = 0x7fffffff;             // lane k holds the k-th pop's index
  float vA = 0.f, vB = 0.f;
  unsigned long long keyLast = 0ull;
  #pragma unroll
  for (int k = 0; k <= ESIM; ++k){
    unsigned long long bk = kv0;
    #pragma unroll
    for (int off=32; off; off>>=1){
      unsigned long long ok = shfl_xor64(bk, off);
      if (ok > bk) bk = ok;
    }
    if (kv0 == bk){ kv0=kv1; kv1=kv2; kv2=kv3; kv3=0ull; }
    if (lane == k) myidx = (int)(~(unsigned int)bk);
    if (k == ESIM-1) vA = inv_map((unsigned int)(bk >> 32));
    if (k == ESIM){ vB = inv_map((unsigned int)(bk >> 32)); keyLast = bk; }
  }

  // exactness: if cert <= keyLast, no discarded key can be in the top-(ESIM+1) -> pops exact
  bool fb = (cert > keyLast) || (vA - vB < TAU);
  if (!fb){
    if (lane < ESIM){
      ssel[lane] = myidx;
      topidx[(size_t)grow*16 + lane] = myidx;
    }
  } else {
    // ========== FALLBACK: radix24 + collect + extract + gap/rescore ==========
    int k1 = min(t, K1);
    unsigned int thr = radix24(srow, t, k1, 0u, sh, lane);

    if (lane == 0){ s_cnt[wid][0] = 0; s_cnt[wid][1] = 0; }
    for (int s4 = lane*4; s4 < t4; s4 += 256){
      float4 f = *(const float4*)&srow[s4];
      unsigned int uu[4] = {fwd_map(f.x), fwd_map(f.y), fwd_map(f.z), fwd_map(f.w)};
      #pragma unroll
      for (int q=0;q<4;q++){
        unsigned int b24 = uu[q] & BMASK;
        if (b24 > thr){ int p = atomicAdd(&s_cnt[wid][0],1); if (p < CANDCAP) scand[p] = s4+q; }
        else if (b24 == thr){ int p = atomicAdd(&s_cnt[wid][1],1); if (p < EQCAP) seq[p] = s4+q; }
      }
    }
    for (int s = t4 + lane; s < t; s += 64){
      unsigned int b24 = fwd_map(srow[s]) & BMASK;
      if (b24 > thr){ int p = atomicAdd(&s_cnt[wid][0],1); if (p < CANDCAP) scand[p] = s; }
      else if (b24 == thr){ int p = atomicAdd(&s_cnt[wid][1],1); if (p < EQCAP) seq[p] = s; }
    }
    int c_gt = min(s_cnt[wid][0], CANDCAP);
    int c_eq = min(s_cnt[wid][1], EQCAP);
    int ncand = min(c_gt + c_eq, 64);

    unsigned int myu = 0u; int myi = 0x7fffffff;
    if (lane < ncand){
      myi = (lane < c_gt) ? scand[lane] : seq[lane - c_gt];
      myu = fwd_map(srow[myi]);
    }

    float fvA = 0.f, fvB = 0.f;
    {
      unsigned int cu = myu; int ci = myi;
      #pragma unroll
      for (int k = 0; k <= ESIM; ++k){
        unsigned int bu = cu; int bi = ci;
        #pragma unroll
        for (int off=32; off; off>>=1){
          unsigned int ou = __shfl_xor(bu, off); int oi = __shfl_xor(bi, off);
          if (ou > bu || (ou == bu && oi < bi)){ bu = ou; bi = oi; }
        }
        if (k < ESIM && lane == 0) ssel[k] = bi;
        if (k == ESIM-1) fvA = inv_map(bu);
        if (k == ESIM)   fvB = inv_map(bu);
        if (ci == bi){ cu = 0u; ci = 0x7fffffff; }
      }
    }

    bool resc = (fvA - fvB < TAU);
    if (resc){
      const float* hq = hb + (size_t)t*DD;
      float rt = rnb[t];
      float4 q0 = *(const float4*)&hq[lane*4];
      float4 q1 = *(const float4*)&hq[lane*4 + 256];
      float ev = NEG_INF;
      for (int j = 0; j < ncand; ++j){
        int idx = (j < c_gt) ? scand[j] : seq[j - c_gt];
        const float* hc = hb + (size_t)idx*DD;
        float4 c0 = *(const float4*)&hc[lane*4];
        float4 c1 = *(const float4*)&hc[lane*4 + 256];
        float pp = q0.x*c0.x+q0.y*c0.y+q0.z*c0.z+q0.w*c0.w
                 + q1.x*c1.x+q1.y*c1.y+q1.z*c1.z+q1.w*c1.w;
        #pragma unroll
        for (int off=32; off; off>>=1) pp += __shfl_xor(pp, off);
        float ex = pp * rt * rnb[idx];
        if (lane == j) ev = ex;
      }
      float rv = (lane < ncand) ? ev : NEG_INF;
      int   ri = myi;
      #pragma unroll
      for (int k = 0; k < ESIM; ++k){
        float bv = rv; int bi = ri;
        #pragma unroll
        for (int off=32; off; off>>=1){
          float ov = __shfl_xor(bv, off); int oi = __shfl_xor(bi, off);
          if (ov > bv || (ov == bv && oi < bi)){ bv = ov; bi = oi; }
        }
        if (lane == 0) ssel[k] = bi;
        if (ri == bi) rv = NEG_INF;
      }
    }
    if (lane < ESIM) topidx[(size_t)grow*16 + lane] = ssel[lane];
  }

  // ---------- BOTTOM path (rows with t > TT-ECON only, <=7 per batch) ----------
  int need = ECON - (TT - t);
  int cnt2 = 0;
  if (need > 0){
    constexpr unsigned int FLIP = 0xFFFFFFFFu;
    int k1b = min(t, K1B);
    unsigned int thrb = radix24(srow, t, k1b, FLIP, sh, lane);

    if (lane == 0){ s_cnt[wid][0] = 0; s_cnt[wid][1] = 0; }
    for (int s4 = lane*4; s4 < t4; s4 += 256){
      float4 f = *(const float4*)&srow[s4];
      unsigned int uu[4] = {fwd_map(f.x)^FLIP, fwd_map(f.y)^FLIP, fwd_map(f.z)^FLIP, fwd_map(f.w)^FLIP};
      #pragma unroll
      for (int q=0;q<4;q++){
        unsigned int b24 = uu[q] & BMASK;
        if (b24 > thrb){ int p = atomicAdd(&s_cnt[wid][0],1); if (p < CANDCAP) scand[p] = s4+q; }
        else if (b24 == thrb){ int p = atomicAdd(&s_cnt[wid][1],1); if (p < EQCAP) seq[p] = s4+q; }
      }
    }
    for (int s = t4 + lane; s < t; s += 64){
      unsigned int u = fwd_map(srow[s])^FLIP;
      unsigned int b24 = u & BMASK;
      if (b24 > thrb){ int p = atomicAdd(&s_cnt[wid][0],1); if (p < CANDCAP) scand[p] = s; }
      else if (b24 == thrb){ int p = atomicAdd(&s_cnt[wid][1],1); if (p < EQCAP) seq[p] = s; }
    }
    int bc_gt = min(s_cnt[wid][0], CANDCAP);
    int bc_eq = min(s_cnt[wid][1], EQCAP);
    int ncb = min(bc_gt + bc_eq, 64);

    unsigned int mu = 0u; int mi = 0x7fffffff;
    if (lane < ncb){
      mi = (lane < bc_gt) ? scand[lane] : seq[lane - bc_gt];
      mu = fwd_map(srow[mi]) ^ FLIP;
    }
    float wA = 0.f, wB = 0.f;
    unsigned int cu = mu; int ci = mi;
    #pragma unroll
    for (int k = 0; k < K1B; ++k){
      if (k < ncb && cnt2 < need + 8){
        unsigned int bu = cu; int bi = ci;
        #pragma unroll
        for (int off=32; off; off>>=1){
          unsigned int ou = __shfl_xor(bu, off); int oi = __shfl_xor(bi, off);
          if (ou > bu || (ou == bu && oi < bi)){ bu = ou; bi = oi; }
        }
        if (ci == bi){ cu = 0u; ci = 0x7fffffff; }
        bool mem = false;
        #pragma unroll
        for (int j=0;j<ESIM;j++) if (ssel[j] == bi) mem = true;
        if (!mem){
          if (lane == 0) sbot[cnt2] = bi;
          float val = inv_map(bu ^ FLIP);
          if (cnt2 == need-1) wA = val;
          if (cnt2 == need)   wB = val;
          cnt2++;
        }
      }
    }
    int npick = min(need, cnt2);
    bool rb = (cnt2 > need) && (wB - wA < TAU);
    if (!rb){
      if (lane < npick) botidx[(size_t)grow*8 + lane] = sbot[lane];
    } else {
      const float* hq = hb + (size_t)t*DD;
      float rt = rnb[t];
      float4 q0 = *(const float4*)&hq[lane*4];
      float4 q1 = *(const float4*)&hq[lane*4 + 256];
      float ev = POS_INF; int ei = 0x7fffffff;
      for (int j = 0; j < cnt2; ++j){
        int idx = sbot[j];
        const float* hc = hb + (size_t)idx*DD;
        float4 c0 = *(const float4*)&hc[lane*4];
        float4 c1 = *(const float4*)&hc[lane*4 + 256];
        float pp = q0.x*c0.x+q0.y*c0.y+q0.z*c0.z+q0.w*c0.w
                 + q1.x*c1.x+q1.y*c1.y+q1.z*c1.z+q1.w*c1.w;
        #pragma unroll
        for (int off=32; off; off>>=1) pp += __shfl_xor(pp, off);
        float ex = pp * rt * rnb[idx];
        if (lane == j){ ev = ex; ei = idx; }
      }
      #pragma unroll
      for (int k = 0; k < ECON; ++k){
        if (k < npick){
          float bv = ev; int bi = ei;
          #pragma unroll
          for (int off=32; off; off>>=1){
            float ov = __shfl_xor(bv, off); int oi = __shfl_xor(bi, off);
            if (ov < bv || (ov == bv && oi < bi)){ bv = ov; bi = oi; }
          }
          if (lane == 0) botidx[(size_t)grow*8 + k] = bi;
          if (ei == bi) ev = POS_INF;
        }
      }
    }
    cnt2 = npick;
  }
  if (lane == 0) bcnt[grow] = cnt2;
}

// ---------------- aggregate + blend + gelu + momentum ----------------
__global__ __launch_bounds__(256) void k_agg(const float* __restrict__ hsrc, float* __restrict__ hdst,
                                             const int* __restrict__ topidx, const int* __restrict__ botidx,
                                             const int* __restrict__ bcnt,
                                             const float* __restrict__ gain, const float* __restrict__ bias,
                                             const float* __restrict__ log_mix, const float* __restrict__ log_alpha,
                                             const float* __restrict__ log_momentum, int r, int eff_sim){
  int row = blockIdx.x;
  int b = row >> 11; int t = row & (TT-1);
  int n_sim = min(eff_sim, t);
  int n_con = bcnt[row];
  float mix      = sigmoidf_(log_mix[r]);
  float alpha    = sigmoidf_(log_alpha[r]);
  float momentum = sigmoidf_(log_momentum[0]);
  const float* hb = hsrc + (size_t)b*TT*DD;

  __shared__ int sidx[16];
  __shared__ int scidx[8];
  if (threadIdx.x < 16) sidx[threadIdx.x]  = (threadIdx.x < n_sim) ? topidx[(size_t)row*16 + threadIdx.x] : 0;
  if (threadIdx.x < 8)  scidx[threadIdx.x] = (threadIdx.x < n_con) ? botidx[(size_t)row*8  + threadIdx.x] : 0;
  __syncthreads();

  #pragma unroll
  for (int e = threadIdx.x; e < DD; e += 256){
    float sp = 0.f;
    for (int j=0;j<n_sim;j++) sp += hb[(size_t)sidx[j]*DD + e];
    float sn = 0.f;
    for (int j=0;j<n_con;j++) sn += hb[(size_t)scidx[j]*DD + e];
    float mp = sp / (float)max(n_sim, 1);
    float mn = sn / (float)max(n_con, 1);
    float ctx = alpha*mp + (1.f-alpha)*mn;
    float hv = hsrc[(size_t)row*DD + e];
    float blended = mix*hv + (1.f-mix)*ctx;
    float u = blended*gain[e] + bias[e];
    float g = 0.5f*u*(1.0f + erff(u*0.7071067811865475f));
    hdst[(size_t)row*DD + e] = momentum*hv + (1.f-momentum)*g;
  }
}

// ---------------- out = (h - x) * scale ----------------
__global__ __launch_bounds__(256) void k_final(const float* __restrict__ hfin, const float* __restrict__ x,
                                               const float* __restrict__ log_scale, float* __restrict__ out, int n){
  float scale = log1pf(expf(log_scale[0])) + 0.01f;
  int i = blockIdx.x*256 + threadIdx.x;
  if (i < n) out[i] = (hfin[i] - x[i]) * scale;
}

extern "C" void kernel_launch(void* const* d_in, const int* in_sizes, int n_in,
                              void* d_out, int out_size, void* d_ws, size_t ws_size,
                              hipStream_t stream) {
  const float* x         = (const float*)d_in[0];
  const float* gain      = (const float*)d_in[1];
  const float* bias      = (const float*)d_in[2];
  const float* log_mix   = (const float*)d_in[3];
  const float* log_alpha = (const float*)d_in[4];
  const float* log_mom   = (const float*)d_in[5];
  const float* log_scale = (const float*)d_in[6];

  float* hA = (float*)d_out;
  char* ws = (char*)d_ws;
  size_t off = 0;
  auto alloc = [&](size_t bytes){ void* p = ws + off; off += (bytes + 255) & ~(size_t)255; return p; };

  float*          hB     = (float*)alloc((size_t)BB*TT*DD*4);
  float*          rnorm  = (float*)alloc((size_t)BB*TT*4);
  int*            topidx = (int*)  alloc((size_t)BB*TT*16*4);
  int*            botidx = (int*)  alloc((size_t)BB*TT*8*4);
  int*            bcnt   = (int*)  alloc((size_t)BB*TT*4);
  unsigned short* Xh     = (unsigned short*)alloc((size_t)BB*TT*DD*2);
  unsigned short* Xl     = (unsigned short*)alloc((size_t)BB*TT*DD*2);

  size_t rem = (ws_size > off) ? (ws_size - off) : 0;
  int cb = (int)(rem / ((size_t)TT*TT*4));
  if (cb < 1) cb = 1;
  if (cb > BB) cb = BB;
  float* sim = (float*)alloc((size_t)cb*TT*TT*4);

  const float* hsrc = x;
  float* hdst = hB;
  const int ks[3] = {4, 8, 16};

  for (int r = 0; r < 3; ++r){
    k_normsplit<<<BB*TT, 64, 0, stream>>>(hsrc, rnorm, Xh, Xl);
    for (int b0 = 0; b0 < BB; b0 += cb){
      int nb = (BB - b0 < cb) ? (BB - b0) : cb;
      dim3 g(136, nb);
      k_sim<<<g, 256, 0, stream>>>(Xh, Xl, sim, b0);
      if (r == 0)      k_topk<4,2><<<nb*TT/4, 256, 0, stream>>>(sim, b0, hsrc, rnorm, topidx, botidx, bcnt);
      else if (r == 1) k_topk<8,4><<<nb*TT/4, 256, 0, stream>>>(sim, b0, hsrc, rnorm, topidx, botidx, bcnt);
      else             k_topk<16,8><<<nb*TT/4, 256, 0, stream>>>(sim, b0, hsrc, rnorm, topidx, botidx, bcnt);
    }
    k_agg<<<BB*TT, 256, 0, stream>>>(hsrc, hdst, topidx, botidx, bcnt,
                                     gain + (size_t)r*DD, bias + (size_t)r*DD,
                                     log_mix, log_alpha, log_mom, r, ks[r]);
    if (r == 0){ hsrc = hB; hdst = hA; }
    else if (r == 1){ hsrc = hA; hdst = hB; }
  }
  k_final<<<(BB*TT*DD)/256, 256, 0, stream>>>(hB, x, log_scale, (float*)d_out, BB*TT*DD);
}